// Round 18
// baseline (580.288 us; speedup 1.0000x reference)
//
#include <hip/hip_runtime.h>
#include <hip/hip_bf16.h>
#include <cstdint>
#include <cstddef>

typedef __attribute__((ext_vector_type(8))) short short8;
typedef __attribute__((ext_vector_type(4))) short short4v;
typedef __attribute__((ext_vector_type(4))) float f32x4;

#define M4      4194304ull     // 4096*1024
#define OUT_ELE 4194304ull

static __device__ __forceinline__ short f2bf(float f) {
  __hip_bfloat16 h = __float2bfloat16(f);
  union { __hip_bfloat16 b; short s; } u; u.b = h; return u.s;
}
static __device__ __forceinline__ float bf2f(short s) {
  union { short s; __hip_bfloat16 b; } u; u.s = s; return __bfloat162float(u.b);
}
static __device__ __forceinline__ void split2(float v, short &hi, short &lo) {
  hi = f2bf(v);
  lo = f2bf(v - bf2f(hi));
}

typedef void __attribute__((address_space(1)))* gas1_t;
typedef void __attribute__((address_space(3)))* las3_t;
static __device__ __forceinline__ void gload16(const void* g, void* l) {
  __builtin_amdgcn_global_load_lds((gas1_t)(void*)g, (las3_t)l, 16, 0, 0);
}

// ---------------- split q/k/v inputs into bf16 hi/lo --------------------
__global__ void k_split_inputs(const float* __restrict__ q, const float* __restrict__ k,
                               const float* __restrict__ v,
                               short* __restrict__ xh, short* __restrict__ xl) {
  int z = blockIdx.y;
  const float* src = (z == 0) ? q : ((z == 1) ? k : v);
  size_t i = ((size_t)blockIdx.x * blockDim.x + threadIdx.x) * 4;
  float4 f = *(const float4*)(src + i);
  size_t o = (size_t)z * M4 + i;
  short h0,l0,h1,l1,h2,l2,h3,l3;
  split2(f.x,h0,l0); split2(f.y,h1,l1); split2(f.z,h2,l2); split2(f.w,h3,l3);
  short4v hv = {h0,h1,h2,h3}, lv = {l0,l1,l2,l3};
  *(short4v*)(xh + o) = hv;
  *(short4v*)(xl + o) = lv;
}

// ------------- transpose + split weights: Wt[n][k] = W[k][n] ------------
__global__ void k_prep_w(const float* __restrict__ Wq, const float* __restrict__ Wk,
                         const float* __restrict__ Wv, const float* __restrict__ Wo,
                         short* __restrict__ wth, short* __restrict__ wtl) {
  int z = blockIdx.z;
  const float* W = (z==0)?Wq:((z==1)?Wk:((z==2)?Wv:Wo));
  __shared__ float tile[32][33];
  int n0 = blockIdx.x * 32, k0 = blockIdx.y * 32;
  int tx = threadIdx.x & 31, ty = threadIdx.x >> 5;
  #pragma unroll
  for (int s = 0; s < 4; ++s)
    tile[ty + 8*s][tx] = W[(size_t)(k0 + ty + 8*s) * 1024 + n0 + tx];
  __syncthreads();
  size_t zb = (size_t)z * 1048576;
  #pragma unroll
  for (int s = 0; s < 4; ++s) {
    float vv = tile[tx][ty + 8*s];
    short hi, lo; split2(vv, hi, lo);
    size_t idx = zb + (size_t)(n0 + ty + 8*s) * 1024 + k0 + tx;
    wth[idx] = hi; wtl[idx] = lo;
  }
}

// -------- gate bilinear precompute: A_t = Wgk diag(Wm_t) Wgq^T ----------
__global__ void k_gateprep(const float* __restrict__ Wgk, const float* __restrict__ Wgq,
                           const float* __restrict__ Wm,
                           const float* __restrict__ bgk, const float* __restrict__ bgq,
                           const float* __restrict__ bm,
                           float* __restrict__ A, float* __restrict__ U,
                           float* __restrict__ Wvec, float* __restrict__ Cc) {
  int t = blockIdx.x / 65;
  int d = blockIdx.x % 65;
  bool isW = (d == 64);
  __shared__ float T[128 * 65];
  __shared__ float sj[512];
  __shared__ float red[256];
  int tid = threadIdx.x;
  for (int j = tid; j < 512; j += 256)
    sj[j] = Wm[(size_t)j * 2 + t] * (isW ? bgk[j] : Wgk[(size_t)d * 512 + j]);
  __syncthreads();
  int grp = tid >> 6, e = tid & 63;
  float acc = 0.f;
  for (int c = 0; c < 4; ++c) {
    int j0 = c * 128;
    __syncthreads();
    for (int it = 0; it < 32; ++it) {
      int lin = it * 256 + tid;
      int jj = lin & 127, ee = lin >> 7;
      T[jj * 65 + ee] = Wgq[(size_t)ee * 512 + j0 + jj];
    }
    __syncthreads();
    for (int jj = grp * 32; jj < grp * 32 + 32; ++jj)
      acc = fmaf(sj[j0 + jj], T[jj * 65 + e], acc);
  }
  red[tid] = acc;
  __syncthreads();
  if (grp == 0) {
    float r = red[e] + red[64 + e] + red[128 + e] + red[192 + e];
    if (isW) Wvec[t * 64 + e] = r;
    else     A[(size_t)t * 4096 + d * 64 + e] = r;
  }
  if (tid == 0) {
    float s = 0.f;
    for (int j = 0; j < 512; ++j) s += sj[j] * bgq[j];
    if (isW) Cc[t] = s + bm[t];
    else     U[t * 64 + d] = s;
  }
}

// ---- split-bf16 GEMM, 128x128 tile, K=1024, global_load_lds staging ----
template<int EPI>
__global__ __launch_bounds__(256) void k_gemm(
    const short* __restrict__ Ah_g, const short* __restrict__ Al_g,
    const short* __restrict__ Bh_g, const short* __restrict__ Bl_g,
    const float* __restrict__ b0, const float* __restrict__ b1, const float* __restrict__ b2,
    float* __restrict__ Cout, short* __restrict__ Oh, short* __restrict__ Ol,
    short* __restrict__ vt_h, short* __restrict__ vt_l) {
  const int K = 1024;
  int z = blockIdx.z;
  const short* Ah = Ah_g + (size_t)z * M4;
  const short* Al = Al_g + (size_t)z * M4;
  const short* Bh = Bh_g + (size_t)z * 1048576;
  const short* Bl = Bl_g + (size_t)z * 1048576;
  const float* bias = (z == 0) ? b0 : ((z == 1) ? b1 : b2);
  int lin = blockIdx.y * 8 + blockIdx.x;
  int wl = (lin & 7) * 32 + (lin >> 3);
  int m0 = (wl >> 3) * 128, n0 = (wl & 7) * 128;
  __shared__ __align__(16) short As_h[4096], As_l[4096], Bs_h[4096], Bs_l[4096];
  int tid = threadIdx.x;
  int l = tid & 63, w = tid >> 6;
  int wr = w >> 1, wc = w & 1;
  int ar = l & 15, ko = (l >> 4) * 8;
  f32x4 acc[4][4];
  #pragma unroll
  for (int m = 0; m < 4; ++m)
    #pragma unroll
    for (int n = 0; n < 4; ++n) acc[m][n] = {0.f,0.f,0.f,0.f};
  for (int kk = 0; kk < K; kk += 32) {
    __syncthreads();
    #pragma unroll
    for (int p = 0; p < 2; ++p) {
      int g = p * 256 + tid;
      int row = g >> 2, gc = (g & 3) * 8;
      size_t as = (size_t)(m0 + row) * K + kk + gc;
      size_t bs = (size_t)(n0 + row) * K + kk + gc;
      int ldb = g * 16;
      gload16(&Ah[as], (char*)As_h + ldb);
      gload16(&Al[as], (char*)As_l + ldb);
      gload16(&Bh[bs], (char*)Bs_h + ldb);
      gload16(&Bl[bs], (char*)Bs_l + ldb);
    }
    __syncthreads();
    short8 aH[4], aL[4], bH[4], bL[4];
    #pragma unroll
    for (int m = 0; m < 4; ++m) {
      int r = (wr * 64 + m * 16 + ar) * 32 + ko;
      aH[m] = *(short8*)&As_h[r];
      aL[m] = *(short8*)&As_l[r];
    }
    #pragma unroll
    for (int n = 0; n < 4; ++n) {
      int r = (wc * 64 + n * 16 + ar) * 32 + ko;
      bH[n] = *(short8*)&Bs_h[r];
      bL[n] = *(short8*)&Bs_l[r];
    }
    #pragma unroll
    for (int m = 0; m < 4; ++m)
      #pragma unroll
      for (int n = 0; n < 4; ++n) {
        acc[m][n] = __builtin_amdgcn_mfma_f32_16x16x32_bf16(aH[m], bH[n], acc[m][n], 0, 0, 0);
        acc[m][n] = __builtin_amdgcn_mfma_f32_16x16x32_bf16(aH[m], bL[n], acc[m][n], 0, 0, 0);
        acc[m][n] = __builtin_amdgcn_mfma_f32_16x16x32_bf16(aL[m], bH[n], acc[m][n], 0, 0, 0);
      }
  }
  #pragma unroll
  for (int m = 0; m < 4; ++m)
    #pragma unroll
    for (int n = 0; n < 4; ++n) {
      int row0 = m0 + wr * 64 + m * 16 + (l >> 4) * 4;
      int col  = n0 + wc * 64 + n * 16 + ar;
      if (EPI == 1) {
        #pragma unroll
        for (int i = 0; i < 4; ++i)
          Cout[(size_t)(row0 + i) * 1024 + col] = acc[m][n][i] + bias[col];
      } else if (z == 2) {
        int bq = row0 >> 11, s = row0 & 2047, hh = col >> 6, dd = col & 63;
        size_t vb = (((size_t)(bq * 16 + hh)) * 64 + dd) * 2048 + s;
        short4v hv, lv;
        #pragma unroll
        for (int i = 0; i < 4; ++i) {
          float vv = acc[m][n][i] + bias[col];
          short hi, lo; split2(vv, hi, lo);
          hv[i] = hi; lv[i] = lo;
        }
        *(short4v*)&vt_h[vb] = hv;
        *(short4v*)&vt_l[vb] = lv;
      } else {
        #pragma unroll
        for (int i = 0; i < 4; ++i) {
          int row = row0 + i;
          int bq = row >> 11, s = row & 2047, hh = col >> 6, dd = col & 63;
          size_t idx = (size_t)z * M4 + (((size_t)(bq * 16 + hh)) * 2048 + s) * 64 + dd;
          float vv = acc[m][n][i] + bias[col];
          short hi, lo; split2(vv, hi, lo);
          Oh[idx] = hi; Ol[idx] = lo;
        }
      }
    }
}

// ------------- gating: M = sigmoid(bilinear), scale qh/kh in place ------
__global__ void k_gate(short* __restrict__ qh_h, short* __restrict__ qh_l,
                       short* __restrict__ kh_h, short* __restrict__ kh_l,
                       const float* __restrict__ A, const float* __restrict__ U,
                       const float* __restrict__ Wvec, const float* __restrict__ Cc) {
  __shared__ float A0s[4096], A1s[4096];
  __shared__ float rowk[4][64];
  int tid = threadIdx.x, w = tid >> 6, l = tid & 63;
  for (int i = tid; i < 4096; i += 256) { A0s[i] = A[i]; A1s[i] = A[4096 + i]; }
  __syncthreads();
  float u0 = U[l], u1 = U[64 + l];
  float w0 = Wvec[l], w1 = Wvec[64 + l];
  float c0 = Cc[0], c1 = Cc[1];
  for (int rr = 0; rr < 16; ++rr) {
    size_t row = (size_t)blockIdx.x * 64 + w * 16 + rr;
    size_t base = row * 64 + l;
    float qv = bf2f(qh_h[base]) + bf2f(qh_l[base]);
    float kv = bf2f(kh_h[base]) + bf2f(kh_l[base]);
    rowk[w][l] = kv;
    float y0 = 0.f, y1 = 0.f;
    for (int dd = 0; dd < 64; ++dd) {
      float kd = rowk[w][dd];
      y0 = fmaf(kd, A0s[dd * 64 + l], y0);
      y1 = fmaf(kd, A1s[dd * 64 + l], y1);
    }
    float p0 = y0 * qv + u0 * kv + w0 * qv;
    float p1 = y1 * qv + u1 * kv + w1 * qv;
    #pragma unroll
    for (int mm = 1; mm < 64; mm <<= 1) { p0 += __shfl_xor(p0, mm); p1 += __shfl_xor(p1, mm); }
    p0 += c0; p1 += c1;
    float M0 = 1.f / (1.f + expf(-p0));
    float M1 = 1.f / (1.f + expf(-p1));
    short hi, lo;
    split2(qv * M0, hi, lo); qh_h[base] = hi; qh_l[base] = lo;
    split2(kv * M1, hi, lo); kh_h[base] = hi; kh_l[base] = lo;
  }
}

// ---- k_sums: pass-1 only (row sums of exp) at high occupancy -----------
// 32KB LDS (K dbuf only) + VGPR<=64 (launch_bounds 512,8) -> 4 blocks/CU
// = 32 waves/CU, 2x the TLP of the fused version. Writes invl to global.
__global__ __launch_bounds__(512, 8) void k_sums(
    const short* __restrict__ ph_h, const short* __restrict__ ph_l,
    const float* __restrict__ mask, float* __restrict__ invl_g) {
  int bid = blockIdx.x;
  int xcd = bid & 7, slot = bid >> 3;
  int bh = (xcd << 2) | (slot >> 4);
  int s0 = (slot & 15) << 7;
  int b = bh >> 4;
  int tid = threadIdx.x, w = tid >> 6, l = tid & 63;
  int ar = l & 15, hi4 = l >> 4, a7 = ar & 7;
  __shared__ __align__(16) short Ksh[2][4096];
  __shared__ __align__(16) short Ksl[2][4096];

  const short* kh_h = ph_h + M4;
  const short* kh_l = ph_l + M4;
  const char* gKh = (const char*)kh_h + (size_t)bh * 2048 * 128;
  const char* gKl = (const char*)kh_l + (size_t)bh * 2048 * 128;
  const float* maskp = mask + (size_t)b * 2048;

  int rowbase = s0 + w * 16;
  size_t qbase = ((size_t)bh * 2048 + rowbase + ar) * 64 + (size_t)hi4 * 8;
  short8 aH0 = *(const short8*)&ph_h[qbase];
  short8 aH1 = *(const short8*)&ph_h[qbase + 32];
  short8 aL0 = *(const short8*)&ph_l[qbase];
  short8 aL1 = *(const short8*)&ph_l[qbase + 32];

  #define STAGE_K(tile, buf) {                                          \
    const char* th_ = gKh + (size_t)(tile) * 8192;                      \
    const char* tl_ = gKl + (size_t)(tile) * 8192;                      \
    int col_ = tid >> 3, j_ = tid & 7;                                  \
    int gs_ = col_ * 128 + ((j_ ^ (col_ & 7)) << 4);                    \
    gload16(th_ + gs_, (char*)&Ksh[buf][0] + tid * 16);                 \
    gload16(tl_ + gs_, (char*)&Ksl[buf][0] + tid * 16);                 \
  }

  float ls[4] = {0.f, 0.f, 0.f, 0.f};

  STAGE_K(0, 0);
  #pragma unroll 1
  for (int t = 0; t < 32; ++t) {
    __syncthreads();
    if (t < 31) STAGE_K(t + 1, (t + 1) & 1);
    const char* kbh_ = (const char*)&Ksh[t & 1][0];
    const char* kbl_ = (const char*)&Ksl[t & 1][0];
    #pragma unroll
    for (int n = 0; n < 4; ++n) {
      int colloc = n * 16 + ar;
      int cb = colloc * 128;
      short8 bH0 = *(const short8*)(kbh_ + cb + ((hi4 ^ a7) << 4));
      short8 bH1 = *(const short8*)(kbh_ + cb + (((hi4 + 4) ^ a7) << 4));
      short8 bL0 = *(const short8*)(kbl_ + cb + ((hi4 ^ a7) << 4));
      short8 bL1 = *(const short8*)(kbl_ + cb + (((hi4 + 4) ^ a7) << 4));
      f32x4 c = {0.f,0.f,0.f,0.f};
      c = __builtin_amdgcn_mfma_f32_16x16x32_bf16(aH0, bH0, c, 0,0,0);
      c = __builtin_amdgcn_mfma_f32_16x16x32_bf16(aH1, bH1, c, 0,0,0);
      c = __builtin_amdgcn_mfma_f32_16x16x32_bf16(aH0, bL0, c, 0,0,0);
      c = __builtin_amdgcn_mfma_f32_16x16x32_bf16(aH1, bL1, c, 0,0,0);
      c = __builtin_amdgcn_mfma_f32_16x16x32_bf16(aL0, bH0, c, 0,0,0);
      c = __builtin_amdgcn_mfma_f32_16x16x32_bf16(aL1, bH1, c, 0,0,0);
      float mv = maskp[t * 64 + colloc] * -1e9f;
      #pragma unroll
      for (int i = 0; i < 4; ++i) ls[i] += __expf(c[i] * 0.125f + mv);
    }
  }
  #pragma unroll
  for (int mk = 1; mk < 16; mk <<= 1)
    #pragma unroll
    for (int i = 0; i < 4; ++i) ls[i] += __shfl_xor(ls[i], mk);
  if (ar == 0) {
    #pragma unroll
    for (int i = 0; i < 4; ++i)
      invl_g[(size_t)bh * 2048 + rowbase + hi4 * 4 + i] = 1.f / ls[i];
  }
  #undef STAGE_K
}

// ---- k_attn2: pass-2 only (P + attn store + PV); reads invl ------------
// LDS 80KB (K dbuf 32 + V dbuf 32 + P 16) = 2 blocks/CU; one barrier/phase.
__global__ __launch_bounds__(512, 4) void k_attn2(
    const short* __restrict__ ph_h, const short* __restrict__ ph_l,
    const short* __restrict__ vt_h, const short* __restrict__ vt_l,
    const float* __restrict__ mask, const float* __restrict__ invl_g,
    float* __restrict__ attn, short* __restrict__ mh_h, short* __restrict__ mh_l) {
  int bid = blockIdx.x;
  int xcd = bid & 7, slot = bid >> 3;
  int bh = (xcd << 2) | (slot >> 4);
  int s0 = (slot & 15) << 7;
  int b = bh >> 4, h = bh & 15;
  int tid = threadIdx.x, w = tid >> 6, l = tid & 63;
  int ar = l & 15, hi4 = l >> 4, a7 = ar & 7;
  __shared__ __align__(16) short Ksh[2][4096];
  __shared__ __align__(16) short Ksl[2][4096];
  __shared__ __align__(16) short Vsh[2][4096];
  __shared__ __align__(16) short Vsl[2][4096];
  __shared__ __align__(16) short Pb[8][1024];

  const short* kh_h = ph_h + M4;
  const short* kh_l = ph_l + M4;
  const char* gKh = (const char*)kh_h + (size_t)bh * 2048 * 128;
  const char* gKl = (const char*)kh_l + (size_t)bh * 2048 * 128;
  const char* gVh = (const char*)vt_h + (size_t)bh * 64 * 4096;
  const char* gVl = (const char*)vt_l + (size_t)bh * 64 * 4096;
  const float* maskp = mask + (size_t)b * 2048;

  int rowbase = s0 + w * 16;
  size_t qbase = ((size_t)bh * 2048 + rowbase + ar) * 64 + (size_t)hi4 * 8;
  short8 aH0 = *(const short8*)&ph_h[qbase];
  short8 aH1 = *(const short8*)&ph_h[qbase + 32];
  short8 aL0 = *(const short8*)&ph_l[qbase];
  short8 aL1 = *(const short8*)&ph_l[qbase + 32];

  float invl[4];
  #pragma unroll
  for (int i = 0; i < 4; ++i)
    invl[i] = invl_g[(size_t)bh * 2048 + rowbase + hi4 * 4 + i];

  #define STAGE_K(tile, buf) {                                          \
    const char* th_ = gKh + (size_t)(tile) * 8192;                      \
    const char* tl_ = gKl + (size_t)(tile) * 8192;                      \
    int col_ = tid >> 3, j_ = tid & 7;                                  \
    int gs_ = col_ * 128 + ((j_ ^ (col_ & 7)) << 4);                    \
    gload16(th_ + gs_, (char*)&Ksh[buf][0] + tid * 16);                 \
    gload16(tl_ + gs_, (char*)&Ksl[buf][0] + tid * 16);                 \
  }

  #define STAGE_V(tile, buf) {                                          \
    int row_ = tid >> 3, j_ = tid & 7;                                  \
    int gs_ = row_ * 4096 + (tile) * 128 + ((j_ ^ (row_ & 7)) << 4);    \
    gload16(gVh + gs_, (char*)&Vsh[buf][0] + tid * 16);                 \
    gload16(gVl + gs_, (char*)&Vsl[buf][0] + tid * 16);                 \
  }

  f32x4 acc[4];
  #pragma unroll
  for (int dn = 0; dn < 4; ++dn) acc[dn] = {0.f,0.f,0.f,0.f};
  size_t arow = (size_t)bh * 2048 + rowbase;

  STAGE_K(0, 0);
  STAGE_V(0, 0);
  #pragma unroll 1
  for (int t = 0; t < 32; ++t) {
    __syncthreads();                       // K(t), V(t) ready (staged t-1)
    if (t < 31) { STAGE_K(t + 1, (t + 1) & 1); STAGE_V(t + 1, (t + 1) & 1); }
    f32x4 lg[4];
    {
      const char* kbh_ = (const char*)&Ksh[t & 1][0];
      const char* kbl_ = (const char*)&Ksl[t & 1][0];
      #pragma unroll
      for (int n = 0; n < 4; ++n) {
        int colloc = n * 16 + ar;
        int cb = colloc * 128;
        short8 bH0 = *(const short8*)(kbh_ + cb + ((hi4 ^ a7) << 4));
        short8 bH1 = *(const short8*)(kbh_ + cb + (((hi4 + 4) ^ a7) << 4));
        short8 bL0 = *(const short8*)(kbl_ + cb + ((hi4 ^ a7) << 4));
        short8 bL1 = *(const short8*)(kbl_ + cb + (((hi4 + 4) ^ a7) << 4));
        f32x4 c = {0.f,0.f,0.f,0.f};
        c = __builtin_amdgcn_mfma_f32_16x16x32_bf16(aH0, bH0, c, 0,0,0);
        c = __builtin_amdgcn_mfma_f32_16x16x32_bf16(aH1, bH1, c, 0,0,0);
        c = __builtin_amdgcn_mfma_f32_16x16x32_bf16(aH0, bL0, c, 0,0,0);
        c = __builtin_amdgcn_mfma_f32_16x16x32_bf16(aH1, bL1, c, 0,0,0);
        c = __builtin_amdgcn_mfma_f32_16x16x32_bf16(aL0, bH0, c, 0,0,0);
        c = __builtin_amdgcn_mfma_f32_16x16x32_bf16(aL1, bH1, c, 0,0,0);
        float mv = maskp[t * 64 + colloc] * -1e9f;
        #pragma unroll
        for (int i = 0; i < 4; ++i) lg[n][i] = c[i] * 0.125f + mv;
      }
    }
    char* pbw = (char*)&Pb[w][0];
    #pragma unroll
    for (int n = 0; n < 4; ++n) {
      #pragma unroll
      for (int i = 0; i < 4; ++i) {
        float p = __expf(lg[n][i]) * invl[i];
        lg[n][i] = p;
        int r = hi4 * 4 + i;
        int off = (r * 128 + (n * 16 + ar) * 2) ^ ((r & 7) << 4);
        *(short*)(pbw + off) = f2bf(p);
      }
    }
    #pragma unroll
    for (int ks = 0; ks < 2; ++ks) {
      int roff = (ar * 128 + ks * 64 + hi4 * 16) ^ (a7 << 4);
      short8 pah = *(const short8*)(pbw + roff);
      #pragma unroll
      for (int dn = 0; dn < 4; ++dn) {
        int voff = (dn * 16 + ar) * 128 + ((ks * 64 + hi4 * 16) ^ (a7 << 4));
        short8 vH = *(const short8*)((const char*)&Vsh[t & 1][0] + voff);
        short8 vL = *(const short8*)((const char*)&Vsl[t & 1][0] + voff);
        acc[dn] = __builtin_amdgcn_mfma_f32_16x16x32_bf16(pah, vH, acc[dn], 0,0,0);
        acc[dn] = __builtin_amdgcn_mfma_f32_16x16x32_bf16(pah, vL, acc[dn], 0,0,0);
      }
    }
    #pragma unroll
    for (int n = 0; n < 4; ++n)
      #pragma unroll
      for (int i = 0; i < 4; ++i)
        __builtin_nontemporal_store(lg[n][i],
            &attn[(arow + hi4 * 4 + i) * 2048 + t * 64 + n * 16 + ar]);
  }
  #pragma unroll
  for (int dn = 0; dn < 4; ++dn)
    #pragma unroll
    for (int i = 0; i < 4; ++i) {
      short hh, ll; split2(acc[dn][i], hh, ll);
      size_t idx = ((size_t)b * 2048 + rowbase + hi4 * 4 + i) * 1024
                 + h * 64 + dn * 16 + ar;
      mh_h[idx] = hh; mh_l[idx] = ll;
    }
  #undef STAGE_K
  #undef STAGE_V
}

// ------------------------------ launcher --------------------------------
extern "C" void kernel_launch(void* const* d_in, const int* in_sizes, int n_in,
                              void* d_out, int out_size, void* d_ws, size_t ws_size,
                              hipStream_t stream) {
  const float* v    = (const float*)d_in[0];
  const float* k    = (const float*)d_in[1];
  const float* q    = (const float*)d_in[2];
  const float* mask = (const float*)d_in[3];
  const float* Wq   = (const float*)d_in[4];
  const float* bq   = (const float*)d_in[5];
  const float* Wk   = (const float*)d_in[6];
  const float* bk   = (const float*)d_in[7];
  const float* Wv   = (const float*)d_in[8];
  const float* bv   = (const float*)d_in[9];
  const float* Wgk  = (const float*)d_in[10];
  const float* bgk  = (const float*)d_in[11];
  const float* Wgq  = (const float*)d_in[12];
  const float* bgq  = (const float*)d_in[13];
  const float* Wm   = (const float*)d_in[14];
  const float* bm   = (const float*)d_in[15];
  const float* Wo   = (const float*)d_in[16];
  const float* bo   = (const float*)d_in[17];
  float* out  = (float*)d_out;
  float* attn = out + OUT_ELE;

  short* xh = (short*)attn;
  short* xl = xh + 3 * M4;

  short* wth  = (short*)d_ws;
  short* wtl  = wth + 4 * 1048576ull;
  short* ph_h = wtl + 4 * 1048576ull;
  short* ph_l = ph_h + 3 * M4;
  short* vt_h = ph_l + 3 * M4;
  short* vt_l = vt_h + M4;
  short* mh_h = vt_l + M4;
  short* mh_l = mh_h + M4;
  float* Ag   = (float*)(mh_l + M4);
  float* Ug   = Ag + 8192;
  float* Wvec = Ug + 128;
  float* Cg   = Wvec + 128;
  float* invl_g = Cg + 64;               // 64K floats (256 KB)

  k_split_inputs<<<dim3(4096, 3), 256, 0, stream>>>(q, k, v, xh, xl);
  k_prep_w<<<dim3(32, 32, 4), 256, 0, stream>>>(Wq, Wk, Wv, Wo, wth, wtl);
  k_gateprep<<<130, 256, 0, stream>>>(Wgk, Wgq, Wm, bgk, bgq, bm, Ag, Ug, Wvec, Cg);
  k_gemm<0><<<dim3(8, 32, 3), 256, 0, stream>>>(xh, xl, wth, wtl, bq, bk, bv,
                                                nullptr, ph_h, ph_l, vt_h, vt_l);
  k_gate<<<1024, 256, 0, stream>>>(ph_h, ph_l, ph_h + M4, ph_l + M4, Ag, Ug, Wvec, Cg);
  k_sums<<<dim3(512), 512, 0, stream>>>(ph_h, ph_l, mask, invl_g);
  k_attn2<<<dim3(512), 512, 0, stream>>>(ph_h, ph_l, vt_h, vt_l, mask, invl_g,
                                         attn, mh_h, mh_l);
  k_gemm<1><<<dim3(8, 32, 1), 256, 0, stream>>>(mh_h, mh_l,
                                                wth + 3 * 1048576ull, wtl + 3 * 1048576ull,
                                                bo, bo, bo, out, nullptr, nullptr,
                                                nullptr, nullptr);
}

// Round 19
// 557.762 us; speedup vs baseline: 1.0404x; 1.0404x over previous
//
#include <hip/hip_runtime.h>
#include <hip/hip_bf16.h>
#include <cstdint>
#include <cstddef>

typedef __attribute__((ext_vector_type(8))) short short8;
typedef __attribute__((ext_vector_type(4))) short short4v;
typedef __attribute__((ext_vector_type(4))) float f32x4;

#define M4      4194304ull     // 4096*1024
#define OUT_ELE 4194304ull

static __device__ __forceinline__ short f2bf(float f) {
  __hip_bfloat16 h = __float2bfloat16(f);
  union { __hip_bfloat16 b; short s; } u; u.b = h; return u.s;
}
static __device__ __forceinline__ float bf2f(short s) {
  union { short s; __hip_bfloat16 b; } u; u.s = s; return __bfloat162float(u.b);
}
static __device__ __forceinline__ void split2(float v, short &hi, short &lo) {
  hi = f2bf(v);
  lo = f2bf(v - bf2f(hi));
}

typedef void __attribute__((address_space(1)))* gas1_t;
typedef void __attribute__((address_space(3)))* las3_t;
static __device__ __forceinline__ void gload16(const void* g, void* l) {
  __builtin_amdgcn_global_load_lds((gas1_t)(void*)g, (las3_t)l, 16, 0, 0);
}

// ---------------- split q/k/v inputs into bf16 hi/lo --------------------
__global__ void k_split_inputs(const float* __restrict__ q, const float* __restrict__ k,
                               const float* __restrict__ v,
                               short* __restrict__ xh, short* __restrict__ xl) {
  int z = blockIdx.y;
  const float* src = (z == 0) ? q : ((z == 1) ? k : v);
  size_t i = ((size_t)blockIdx.x * blockDim.x + threadIdx.x) * 4;
  float4 f = *(const float4*)(src + i);
  size_t o = (size_t)z * M4 + i;
  short h0,l0,h1,l1,h2,l2,h3,l3;
  split2(f.x,h0,l0); split2(f.y,h1,l1); split2(f.z,h2,l2); split2(f.w,h3,l3);
  short4v hv = {h0,h1,h2,h3}, lv = {l0,l1,l2,l3};
  *(short4v*)(xh + o) = hv;
  *(short4v*)(xl + o) = lv;
}

// ------------- transpose + split weights: Wt[n][k] = W[k][n] ------------
__global__ void k_prep_w(const float* __restrict__ Wq, const float* __restrict__ Wk,
                         const float* __restrict__ Wv, const float* __restrict__ Wo,
                         short* __restrict__ wth, short* __restrict__ wtl) {
  int z = blockIdx.z;
  const float* W = (z==0)?Wq:((z==1)?Wk:((z==2)?Wv:Wo));
  __shared__ float tile[32][33];
  int n0 = blockIdx.x * 32, k0 = blockIdx.y * 32;
  int tx = threadIdx.x & 31, ty = threadIdx.x >> 5;
  #pragma unroll
  for (int s = 0; s < 4; ++s)
    tile[ty + 8*s][tx] = W[(size_t)(k0 + ty + 8*s) * 1024 + n0 + tx];
  __syncthreads();
  size_t zb = (size_t)z * 1048576;
  #pragma unroll
  for (int s = 0; s < 4; ++s) {
    float vv = tile[tx][ty + 8*s];
    short hi, lo; split2(vv, hi, lo);
    size_t idx = zb + (size_t)(n0 + ty + 8*s) * 1024 + k0 + tx;
    wth[idx] = hi; wtl[idx] = lo;
  }
}

// -------- gate bilinear precompute: A_t = Wgk diag(Wm_t) Wgq^T ----------
__global__ void k_gateprep(const float* __restrict__ Wgk, const float* __restrict__ Wgq,
                           const float* __restrict__ Wm,
                           const float* __restrict__ bgk, const float* __restrict__ bgq,
                           const float* __restrict__ bm,
                           float* __restrict__ A, float* __restrict__ U,
                           float* __restrict__ Wvec, float* __restrict__ Cc) {
  int t = blockIdx.x / 65;
  int d = blockIdx.x % 65;
  bool isW = (d == 64);
  __shared__ float T[128 * 65];
  __shared__ float sj[512];
  __shared__ float red[256];
  int tid = threadIdx.x;
  for (int j = tid; j < 512; j += 256)
    sj[j] = Wm[(size_t)j * 2 + t] * (isW ? bgk[j] : Wgk[(size_t)d * 512 + j]);
  __syncthreads();
  int grp = tid >> 6, e = tid & 63;
  float acc = 0.f;
  for (int c = 0; c < 4; ++c) {
    int j0 = c * 128;
    __syncthreads();
    for (int it = 0; it < 32; ++it) {
      int lin = it * 256 + tid;
      int jj = lin & 127, ee = lin >> 7;
      T[jj * 65 + ee] = Wgq[(size_t)ee * 512 + j0 + jj];
    }
    __syncthreads();
    for (int jj = grp * 32; jj < grp * 32 + 32; ++jj)
      acc = fmaf(sj[j0 + jj], T[jj * 65 + e], acc);
  }
  red[tid] = acc;
  __syncthreads();
  if (grp == 0) {
    float r = red[e] + red[64 + e] + red[128 + e] + red[192 + e];
    if (isW) Wvec[t * 64 + e] = r;
    else     A[(size_t)t * 4096 + d * 64 + e] = r;
  }
  if (tid == 0) {
    float s = 0.f;
    for (int j = 0; j < 512; ++j) s += sj[j] * bgq[j];
    if (isW) Cc[t] = s + bm[t];
    else     U[t * 64 + d] = s;
  }
}

// ---- split-bf16 GEMM, 128x128 tile, K=1024, global_load_lds staging ----
template<int EPI>
__global__ __launch_bounds__(256) void k_gemm(
    const short* __restrict__ Ah_g, const short* __restrict__ Al_g,
    const short* __restrict__ Bh_g, const short* __restrict__ Bl_g,
    const float* __restrict__ b0, const float* __restrict__ b1, const float* __restrict__ b2,
    float* __restrict__ Cout, short* __restrict__ Oh, short* __restrict__ Ol,
    short* __restrict__ vt_h, short* __restrict__ vt_l) {
  const int K = 1024;
  int z = blockIdx.z;
  const short* Ah = Ah_g + (size_t)z * M4;
  const short* Al = Al_g + (size_t)z * M4;
  const short* Bh = Bh_g + (size_t)z * 1048576;
  const short* Bl = Bl_g + (size_t)z * 1048576;
  const float* bias = (z == 0) ? b0 : ((z == 1) ? b1 : b2);
  int lin = blockIdx.y * 8 + blockIdx.x;
  int wl = (lin & 7) * 32 + (lin >> 3);
  int m0 = (wl >> 3) * 128, n0 = (wl & 7) * 128;
  __shared__ __align__(16) short As_h[4096], As_l[4096], Bs_h[4096], Bs_l[4096];
  int tid = threadIdx.x;
  int l = tid & 63, w = tid >> 6;
  int wr = w >> 1, wc = w & 1;
  int ar = l & 15, ko = (l >> 4) * 8;
  f32x4 acc[4][4];
  #pragma unroll
  for (int m = 0; m < 4; ++m)
    #pragma unroll
    for (int n = 0; n < 4; ++n) acc[m][n] = {0.f,0.f,0.f,0.f};
  for (int kk = 0; kk < K; kk += 32) {
    __syncthreads();
    #pragma unroll
    for (int p = 0; p < 2; ++p) {
      int g = p * 256 + tid;
      int row = g >> 2, gc = (g & 3) * 8;
      size_t as = (size_t)(m0 + row) * K + kk + gc;
      size_t bs = (size_t)(n0 + row) * K + kk + gc;
      int ldb = g * 16;
      gload16(&Ah[as], (char*)As_h + ldb);
      gload16(&Al[as], (char*)As_l + ldb);
      gload16(&Bh[bs], (char*)Bs_h + ldb);
      gload16(&Bl[bs], (char*)Bs_l + ldb);
    }
    __syncthreads();
    short8 aH[4], aL[4], bH[4], bL[4];
    #pragma unroll
    for (int m = 0; m < 4; ++m) {
      int r = (wr * 64 + m * 16 + ar) * 32 + ko;
      aH[m] = *(short8*)&As_h[r];
      aL[m] = *(short8*)&As_l[r];
    }
    #pragma unroll
    for (int n = 0; n < 4; ++n) {
      int r = (wc * 64 + n * 16 + ar) * 32 + ko;
      bH[n] = *(short8*)&Bs_h[r];
      bL[n] = *(short8*)&Bs_l[r];
    }
    #pragma unroll
    for (int m = 0; m < 4; ++m)
      #pragma unroll
      for (int n = 0; n < 4; ++n) {
        acc[m][n] = __builtin_amdgcn_mfma_f32_16x16x32_bf16(aH[m], bH[n], acc[m][n], 0, 0, 0);
        acc[m][n] = __builtin_amdgcn_mfma_f32_16x16x32_bf16(aH[m], bL[n], acc[m][n], 0, 0, 0);
        acc[m][n] = __builtin_amdgcn_mfma_f32_16x16x32_bf16(aL[m], bH[n], acc[m][n], 0, 0, 0);
      }
  }
  #pragma unroll
  for (int m = 0; m < 4; ++m)
    #pragma unroll
    for (int n = 0; n < 4; ++n) {
      int row0 = m0 + wr * 64 + m * 16 + (l >> 4) * 4;
      int col  = n0 + wc * 64 + n * 16 + ar;
      if (EPI == 1) {
        #pragma unroll
        for (int i = 0; i < 4; ++i)
          Cout[(size_t)(row0 + i) * 1024 + col] = acc[m][n][i] + bias[col];
      } else if (z == 2) {
        int bq = row0 >> 11, s = row0 & 2047, hh = col >> 6, dd = col & 63;
        size_t vb = (((size_t)(bq * 16 + hh)) * 64 + dd) * 2048 + s;
        short4v hv, lv;
        #pragma unroll
        for (int i = 0; i < 4; ++i) {
          float vv = acc[m][n][i] + bias[col];
          short hi, lo; split2(vv, hi, lo);
          hv[i] = hi; lv[i] = lo;
        }
        *(short4v*)&vt_h[vb] = hv;
        *(short4v*)&vt_l[vb] = lv;
      } else {
        #pragma unroll
        for (int i = 0; i < 4; ++i) {
          int row = row0 + i;
          int bq = row >> 11, s = row & 2047, hh = col >> 6, dd = col & 63;
          size_t idx = (size_t)z * M4 + (((size_t)(bq * 16 + hh)) * 2048 + s) * 64 + dd;
          float vv = acc[m][n][i] + bias[col];
          short hi, lo; split2(vv, hi, lo);
          Oh[idx] = hi; Ol[idx] = lo;
        }
      }
    }
}

// ------------- gating: M = sigmoid(bilinear), scale qh/kh in place ------
__global__ void k_gate(short* __restrict__ qh_h, short* __restrict__ qh_l,
                       short* __restrict__ kh_h, short* __restrict__ kh_l,
                       const float* __restrict__ A, const float* __restrict__ U,
                       const float* __restrict__ Wvec, const float* __restrict__ Cc) {
  __shared__ float A0s[4096], A1s[4096];
  __shared__ float rowk[4][64];
  int tid = threadIdx.x, w = tid >> 6, l = tid & 63;
  for (int i = tid; i < 4096; i += 256) { A0s[i] = A[i]; A1s[i] = A[4096 + i]; }
  __syncthreads();
  float u0 = U[l], u1 = U[64 + l];
  float w0 = Wvec[l], w1 = Wvec[64 + l];
  float c0 = Cc[0], c1 = Cc[1];
  for (int rr = 0; rr < 16; ++rr) {
    size_t row = (size_t)blockIdx.x * 64 + w * 16 + rr;
    size_t base = row * 64 + l;
    float qv = bf2f(qh_h[base]) + bf2f(qh_l[base]);
    float kv = bf2f(kh_h[base]) + bf2f(kh_l[base]);
    rowk[w][l] = kv;
    float y0 = 0.f, y1 = 0.f;
    for (int dd = 0; dd < 64; ++dd) {
      float kd = rowk[w][dd];
      y0 = fmaf(kd, A0s[dd * 64 + l], y0);
      y1 = fmaf(kd, A1s[dd * 64 + l], y1);
    }
    float p0 = y0 * qv + u0 * kv + w0 * qv;
    float p1 = y1 * qv + u1 * kv + w1 * qv;
    #pragma unroll
    for (int mm = 1; mm < 64; mm <<= 1) { p0 += __shfl_xor(p0, mm); p1 += __shfl_xor(p1, mm); }
    p0 += c0; p1 += c1;
    float M0 = 1.f / (1.f + expf(-p0));
    float M1 = 1.f / (1.f + expf(-p1));
    short hi, lo;
    split2(qv * M0, hi, lo); qh_h[base] = hi; qh_l[base] = lo;
    split2(kv * M1, hi, lo); kh_h[base] = hi; kh_l[base] = lo;
  }
}

// ---- fused attention v13: K AND V double-buffered one phase ahead ------
// block = 512 thr / 8 waves, 128 q-rows of one (b,h); grid 512 (1D),
// XCD-grouped. LDS 80KB (K dbuf 32 + V dbuf 32 + P 16) = 2 blocks/CU;
// mask read from global (L2-hot). P is WAVE-PRIVATE -> no barrier needed;
// V(t) staged at phase t-1 -> ONE barrier per phase, no mid-phase sync.
__global__ __launch_bounds__(512, 4) void k_attn(
    const short* __restrict__ ph_h, const short* __restrict__ ph_l,
    const short* __restrict__ vt_h, const short* __restrict__ vt_l,
    const float* __restrict__ mask,
    float* __restrict__ attn, short* __restrict__ mh_h, short* __restrict__ mh_l) {
  int bid = blockIdx.x;
  int xcd = bid & 7, slot = bid >> 3;
  int bh = (xcd << 2) | (slot >> 4);
  int s0 = (slot & 15) << 7;
  int b = bh >> 4, h = bh & 15;
  int tid = threadIdx.x, w = tid >> 6, l = tid & 63;
  int ar = l & 15, hi4 = l >> 4, a7 = ar & 7;
  __shared__ __align__(16) short Ksh[2][4096];   // [buf][64 cols][64]  16KB
  __shared__ __align__(16) short Ksl[2][4096];   //                     16KB
  __shared__ __align__(16) short Vsh[2][4096];   // [buf][64 d][64 k]   16KB
  __shared__ __align__(16) short Vsl[2][4096];   //                     16KB
  __shared__ __align__(16) short Pb[8][1024];    // per-wave P bf16     16KB

  const short* kh_h = ph_h + M4;
  const short* kh_l = ph_l + M4;
  const char* gKh = (const char*)kh_h + (size_t)bh * 2048 * 128;  // rows x 128B
  const char* gKl = (const char*)kh_l + (size_t)bh * 2048 * 128;
  const char* gVh = (const char*)vt_h + (size_t)bh * 64 * 4096;   // 64 d x 4KB
  const char* gVl = (const char*)vt_l + (size_t)bh * 64 * 4096;
  const float* maskp = mask + (size_t)b * 2048;

  int rowbase = s0 + w * 16;
  size_t qbase = ((size_t)bh * 2048 + rowbase + ar) * 64 + (size_t)hi4 * 8;
  short8 aH0 = *(const short8*)&ph_h[qbase];
  short8 aH1 = *(const short8*)&ph_h[qbase + 32];
  short8 aL0 = *(const short8*)&ph_l[qbase];
  short8 aL1 = *(const short8*)&ph_l[qbase + 32];

  #define STAGE_K(tile, buf) {                                          \
    const char* th_ = gKh + (size_t)(tile) * 8192;                      \
    const char* tl_ = gKl + (size_t)(tile) * 8192;                      \
    int col_ = tid >> 3, j_ = tid & 7;                                  \
    int gs_ = col_ * 128 + ((j_ ^ (col_ & 7)) << 4);                    \
    gload16(th_ + gs_, (char*)&Ksh[buf][0] + tid * 16);                 \
    gload16(tl_ + gs_, (char*)&Ksl[buf][0] + tid * 16);                 \
  }

  #define STAGE_V(tile, buf) {                                          \
    int row_ = tid >> 3, j_ = tid & 7;                                  \
    int gs_ = row_ * 4096 + (tile) * 128 + ((j_ ^ (row_ & 7)) << 4);    \
    gload16(gVh + gs_, (char*)&Vsh[buf][0] + tid * 16);                 \
    gload16(gVl + gs_, (char*)&Vsl[buf][0] + tid * 16);                 \
  }

  #define QKT(buf, tile) {                                              \
    const char* kbh_ = (const char*)&Ksh[buf][0];                       \
    const char* kbl_ = (const char*)&Ksl[buf][0];                       \
    _Pragma("unroll")                                                   \
    for (int n = 0; n < 4; ++n) {                                       \
      int colloc = n * 16 + ar;                                         \
      int cb = colloc * 128;                                            \
      short8 bH0 = *(const short8*)(kbh_ + cb + ((hi4 ^ a7) << 4));     \
      short8 bH1 = *(const short8*)(kbh_ + cb + (((hi4 + 4) ^ a7) << 4));\
      short8 bL0 = *(const short8*)(kbl_ + cb + ((hi4 ^ a7) << 4));     \
      short8 bL1 = *(const short8*)(kbl_ + cb + (((hi4 + 4) ^ a7) << 4));\
      f32x4 c = {0.f,0.f,0.f,0.f};                                      \
      c = __builtin_amdgcn_mfma_f32_16x16x32_bf16(aH0, bH0, c, 0,0,0);  \
      c = __builtin_amdgcn_mfma_f32_16x16x32_bf16(aH1, bH1, c, 0,0,0);  \
      c = __builtin_amdgcn_mfma_f32_16x16x32_bf16(aH0, bL0, c, 0,0,0);  \
      c = __builtin_amdgcn_mfma_f32_16x16x32_bf16(aH1, bL1, c, 0,0,0);  \
      c = __builtin_amdgcn_mfma_f32_16x16x32_bf16(aL0, bH0, c, 0,0,0);  \
      c = __builtin_amdgcn_mfma_f32_16x16x32_bf16(aL1, bH1, c, 0,0,0);  \
      float mv = maskp[(tile) * 64 + colloc] * -1e9f;                   \
      _Pragma("unroll")                                                 \
      for (int i = 0; i < 4; ++i) lg[n][i] = c[i] * 0.125f + mv;        \
    } }

  float ls[4] = {0.f, 0.f, 0.f, 0.f};

  STAGE_K(0, 0);
  // ---------------- pass 1: row sums of exp(lg) ----------------
  #pragma unroll 1
  for (int t = 0; t < 32; ++t) {
    __syncthreads();                       // drains STAGE_K(t)
    STAGE_K((t + 1) & 31, (t + 1) & 1);    // t=31 stages tile 0 for pass 2
    f32x4 lg[4];
    QKT(t & 1, t);
    #pragma unroll
    for (int n = 0; n < 4; ++n)
      #pragma unroll
      for (int i = 0; i < 4; ++i) ls[i] += __expf(lg[n][i]);
  }
  #pragma unroll
  for (int mk = 1; mk < 16; mk <<= 1)
    #pragma unroll
    for (int i = 0; i < 4; ++i) ls[i] += __shfl_xor(ls[i], mk);
  float invl[4];
  #pragma unroll
  for (int i = 0; i < 4; ++i) invl[i] = 1.f / ls[i];

  // ---- pass 2: single barrier per phase; V dbuf'd one phase ahead ------
  f32x4 acc[4];
  #pragma unroll
  for (int dn = 0; dn < 4; ++dn) acc[dn] = {0.f,0.f,0.f,0.f};
  size_t arow = (size_t)bh * 2048 + rowbase;

  STAGE_V(0, 0);                           // V(0); lands by first barrier
  #pragma unroll 1
  for (int t = 0; t < 32; ++t) {
    __syncthreads();                       // K(t), V(t) ready (staged t-1)
    if (t < 31) { STAGE_K(t + 1, (t + 1) & 1); STAGE_V(t + 1, (t + 1) & 1); }
    f32x4 lg[4];
    QKT(t & 1, t);
    char* pbw = (char*)&Pb[w][0];
    #pragma unroll
    for (int n = 0; n < 4; ++n) {
      #pragma unroll
      for (int i = 0; i < 4; ++i) {
        float p = __expf(lg[n][i]) * invl[i];
        lg[n][i] = p;
        int r = hi4 * 4 + i;
        int off = (r * 128 + (n * 16 + ar) * 2) ^ ((r & 7) << 4);
        *(short*)(pbw + off) = f2bf(p);
      }
    }
    // PV: P wave-private, V(t) from LDS (guaranteed by top barrier)
    #pragma unroll
    for (int ks = 0; ks < 2; ++ks) {
      int roff = (ar * 128 + ks * 64 + hi4 * 16) ^ (a7 << 4);
      short8 pah = *(const short8*)(pbw + roff);
      #pragma unroll
      for (int dn = 0; dn < 4; ++dn) {
        int voff = (dn * 16 + ar) * 128 + ((ks * 64 + hi4 * 16) ^ (a7 << 4));
        short8 vH = *(const short8*)((const char*)&Vsh[t & 1][0] + voff);
        short8 vL = *(const short8*)((const char*)&Vsl[t & 1][0] + voff);
        acc[dn] = __builtin_amdgcn_mfma_f32_16x16x32_bf16(pah, vH, acc[dn], 0,0,0);
        acc[dn] = __builtin_amdgcn_mfma_f32_16x16x32_bf16(pah, vL, acc[dn], 0,0,0);
      }
    }
    // NT attn stores (drain at next phase's barrier)
    #pragma unroll
    for (int n = 0; n < 4; ++n)
      #pragma unroll
      for (int i = 0; i < 4; ++i)
        __builtin_nontemporal_store(lg[n][i],
            &attn[(arow + hi4 * 4 + i) * 2048 + t * 64 + n * 16 + ar]);
  }
  // ---- epilogue: write mh (bf16 hi/lo) directly from acc ----
  #pragma unroll
  for (int dn = 0; dn < 4; ++dn)
    #pragma unroll
    for (int i = 0; i < 4; ++i) {
      short hh, ll; split2(acc[dn][i], hh, ll);
      size_t idx = ((size_t)b * 2048 + rowbase + hi4 * 4 + i) * 1024
                 + h * 64 + dn * 16 + ar;
      mh_h[idx] = hh; mh_l[idx] = ll;
    }
  #undef STAGE_K
  #undef STAGE_V
  #undef QKT
}

// ------------------------------ launcher --------------------------------
extern "C" void kernel_launch(void* const* d_in, const int* in_sizes, int n_in,
                              void* d_out, int out_size, void* d_ws, size_t ws_size,
                              hipStream_t stream) {
  const float* v    = (const float*)d_in[0];
  const float* k    = (const float*)d_in[1];
  const float* q    = (const float*)d_in[2];
  const float* mask = (const float*)d_in[3];
  const float* Wq   = (const float*)d_in[4];
  const float* bq   = (const float*)d_in[5];
  const float* Wk   = (const float*)d_in[6];
  const float* bk   = (const float*)d_in[7];
  const float* Wv   = (const float*)d_in[8];
  const float* bv   = (const float*)d_in[9];
  const float* Wgk  = (const float*)d_in[10];
  const float* bgk  = (const float*)d_in[11];
  const float* Wgq  = (const float*)d_in[12];
  const float* bgq  = (const float*)d_in[13];
  const float* Wm   = (const float*)d_in[14];
  const float* bm   = (const float*)d_in[15];
  const float* Wo   = (const float*)d_in[16];
  const float* bo   = (const float*)d_in[17];
  float* out  = (float*)d_out;
  float* attn = out + OUT_ELE;

  short* xh = (short*)attn;
  short* xl = xh + 3 * M4;

  short* wth  = (short*)d_ws;
  short* wtl  = wth + 4 * 1048576ull;
  short* ph_h = wtl + 4 * 1048576ull;
  short* ph_l = ph_h + 3 * M4;
  short* vt_h = ph_l + 3 * M4;
  short* vt_l = vt_h + M4;
  short* mh_h = vt_l + M4;
  short* mh_l = mh_h + M4;
  float* Ag   = (float*)(mh_l + M4);
  float* Ug   = Ag + 8192;
  float* Wvec = Ug + 128;
  float* Cg   = Wvec + 128;

  k_split_inputs<<<dim3(4096, 3), 256, 0, stream>>>(q, k, v, xh, xl);
  k_prep_w<<<dim3(32, 32, 4), 256, 0, stream>>>(Wq, Wk, Wv, Wo, wth, wtl);
  k_gateprep<<<130, 256, 0, stream>>>(Wgk, Wgq, Wm, bgk, bgq, bm, Ag, Ug, Wvec, Cg);
  k_gemm<0><<<dim3(8, 32, 3), 256, 0, stream>>>(xh, xl, wth, wtl, bq, bk, bv,
                                                nullptr, ph_h, ph_l, vt_h, vt_l);
  k_gate<<<1024, 256, 0, stream>>>(ph_h, ph_l, ph_h + M4, ph_l + M4, Ag, Ug, Wvec, Cg);
  k_attn<<<dim3(512), 512, 0, stream>>>(ph_h, ph_l, vt_h, vt_l, mask,
                                        attn, mh_h, mh_l);
  k_gemm<1><<<dim3(8, 32, 1), 256, 0, stream>>>(mh_h, mh_l,
                                                wth + 3 * 1048576ull, wtl + 3 * 1048576ull,
                                                bo, bo, bo, out, nullptr, nullptr,
                                                nullptr, nullptr);
}

// Round 20
// 543.835 us; speedup vs baseline: 1.0670x; 1.0256x over previous
//
#include <hip/hip_runtime.h>
#include <hip/hip_bf16.h>
#include <cstdint>
#include <cstddef>

typedef __attribute__((ext_vector_type(8))) short short8;
typedef __attribute__((ext_vector_type(4))) short short4v;
typedef __attribute__((ext_vector_type(4))) float f32x4;

#define M4      4194304ull     // 4096*1024
#define OUT_ELE 4194304ull

static __device__ __forceinline__ short f2bf(float f) {
  __hip_bfloat16 h = __float2bfloat16(f);
  union { __hip_bfloat16 b; short s; } u; u.b = h; return u.s;
}
static __device__ __forceinline__ float bf2f(short s) {
  union { short s; __hip_bfloat16 b; } u; u.s = s; return __bfloat162float(u.b);
}
static __device__ __forceinline__ void split2(float v, short &hi, short &lo) {
  hi = f2bf(v);
  lo = f2bf(v - bf2f(hi));
}

typedef void __attribute__((address_space(1)))* gas1_t;
typedef void __attribute__((address_space(3)))* las3_t;
static __device__ __forceinline__ void gload16(const void* g, void* l) {
  __builtin_amdgcn_global_load_lds((gas1_t)(void*)g, (las3_t)l, 16, 0, 0);
}

// ---- fused prologue: input split + weight transpose + gate precompute ---
// flat grid: [0,12288) split q/k/v; [12288,16384) W transpose; rest gateprep
__global__ __launch_bounds__(256) void k_prep(
    const float* __restrict__ q, const float* __restrict__ k,
    const float* __restrict__ v,
    short* __restrict__ xh, short* __restrict__ xl,
    const float* __restrict__ Wq, const float* __restrict__ Wk,
    const float* __restrict__ Wv, const float* __restrict__ Wo,
    short* __restrict__ wth, short* __restrict__ wtl,
    const float* __restrict__ Wgk, const float* __restrict__ Wgq,
    const float* __restrict__ Wm,
    const float* __restrict__ bgk, const float* __restrict__ bgq,
    const float* __restrict__ bm,
    float* __restrict__ A, float* __restrict__ U,
    float* __restrict__ Wvec, float* __restrict__ Cc) {
  __shared__ float T[128 * 65];          // gateprep main; aliased by prep_w
  __shared__ float sj[512];
  __shared__ float red[256];
  int bid = blockIdx.x;
  int tid = threadIdx.x;

  if (bid < 12288) {
    // -------- input split --------
    int z = bid >> 12;
    const float* src = (z == 0) ? q : ((z == 1) ? k : v);
    size_t i = ((size_t)(bid & 4095) * 256 + tid) * 4;
    float4 f = *(const float4*)(src + i);
    size_t o = (size_t)z * M4 + i;
    short h0,l0,h1,l1,h2,l2,h3,l3;
    split2(f.x,h0,l0); split2(f.y,h1,l1); split2(f.z,h2,l2); split2(f.w,h3,l3);
    short4v hv = {h0,h1,h2,h3}, lv = {l0,l1,l2,l3};
    *(short4v*)(xh + o) = hv;
    *(short4v*)(xl + o) = lv;
  } else if (bid < 16384) {
    // -------- weight transpose + split --------
    int r = bid - 12288;
    int z = r >> 10, rem = r & 1023;
    int n0 = (rem & 31) * 32, k0 = (rem >> 5) * 32;
    const float* W = (z==0)?Wq:((z==1)?Wk:((z==2)?Wv:Wo));
    float (*tile)[33] = (float(*)[33])T;   // alias: 4224B <= 33280B
    int tx = tid & 31, ty = tid >> 5;
    #pragma unroll
    for (int s = 0; s < 4; ++s)
      tile[ty + 8*s][tx] = W[(size_t)(k0 + ty + 8*s) * 1024 + n0 + tx];
    __syncthreads();
    size_t zb = (size_t)z * 1048576;
    #pragma unroll
    for (int s = 0; s < 4; ++s) {
      float vv = tile[tx][ty + 8*s];
      short hi, lo; split2(vv, hi, lo);
      size_t idx = zb + (size_t)(n0 + ty + 8*s) * 1024 + k0 + tx;
      wth[idx] = hi; wtl[idx] = lo;
    }
  } else {
    // -------- gate bilinear precompute --------
    int bb = bid - 16384;
    int t = bb / 65;
    int d = bb % 65;
    bool isW = (d == 64);
    for (int j = tid; j < 512; j += 256)
      sj[j] = Wm[(size_t)j * 2 + t] * (isW ? bgk[j] : Wgk[(size_t)d * 512 + j]);
    __syncthreads();
    int grp = tid >> 6, e = tid & 63;
    float acc = 0.f;
    for (int c = 0; c < 4; ++c) {
      int j0 = c * 128;
      __syncthreads();
      for (int it = 0; it < 32; ++it) {
        int lin = it * 256 + tid;
        int jj = lin & 127, ee = lin >> 7;
        T[jj * 65 + ee] = Wgq[(size_t)ee * 512 + j0 + jj];
      }
      __syncthreads();
      for (int jj = grp * 32; jj < grp * 32 + 32; ++jj)
        acc = fmaf(sj[j0 + jj], T[jj * 65 + e], acc);
    }
    red[tid] = acc;
    __syncthreads();
    if (grp == 0) {
      float r2 = red[e] + red[64 + e] + red[128 + e] + red[192 + e];
      if (isW) Wvec[t * 64 + e] = r2;
      else     A[(size_t)t * 4096 + d * 64 + e] = r2;
    }
    if (tid == 0) {
      float s = 0.f;
      for (int j = 0; j < 512; ++j) s += sj[j] * bgq[j];
      if (isW) Cc[t] = s + bm[t];
      else     U[t * 64 + d] = s;
    }
  }
}

// ---- split-bf16 GEMM, 128x128 tile, K=1024, global_load_lds staging ----
template<int EPI>
__global__ __launch_bounds__(256) void k_gemm(
    const short* __restrict__ Ah_g, const short* __restrict__ Al_g,
    const short* __restrict__ Bh_g, const short* __restrict__ Bl_g,
    const float* __restrict__ b0, const float* __restrict__ b1, const float* __restrict__ b2,
    float* __restrict__ Cout, short* __restrict__ Oh, short* __restrict__ Ol,
    short* __restrict__ vt_h, short* __restrict__ vt_l) {
  const int K = 1024;
  int z = blockIdx.z;
  const short* Ah = Ah_g + (size_t)z * M4;
  const short* Al = Al_g + (size_t)z * M4;
  const short* Bh = Bh_g + (size_t)z * 1048576;
  const short* Bl = Bl_g + (size_t)z * 1048576;
  const float* bias = (z == 0) ? b0 : ((z == 1) ? b1 : b2);
  int lin = blockIdx.y * 8 + blockIdx.x;
  int wl = (lin & 7) * 32 + (lin >> 3);
  int m0 = (wl >> 3) * 128, n0 = (wl & 7) * 128;
  __shared__ __align__(16) short As_h[4096], As_l[4096], Bs_h[4096], Bs_l[4096];
  int tid = threadIdx.x;
  int l = tid & 63, w = tid >> 6;
  int wr = w >> 1, wc = w & 1;
  int ar = l & 15, ko = (l >> 4) * 8;
  f32x4 acc[4][4];
  #pragma unroll
  for (int m = 0; m < 4; ++m)
    #pragma unroll
    for (int n = 0; n < 4; ++n) acc[m][n] = {0.f,0.f,0.f,0.f};
  for (int kk = 0; kk < K; kk += 32) {
    __syncthreads();
    #pragma unroll
    for (int p = 0; p < 2; ++p) {
      int g = p * 256 + tid;
      int row = g >> 2, gc = (g & 3) * 8;
      size_t as = (size_t)(m0 + row) * K + kk + gc;
      size_t bs = (size_t)(n0 + row) * K + kk + gc;
      int ldb = g * 16;
      gload16(&Ah[as], (char*)As_h + ldb);
      gload16(&Al[as], (char*)As_l + ldb);
      gload16(&Bh[bs], (char*)Bs_h + ldb);
      gload16(&Bl[bs], (char*)Bs_l + ldb);
    }
    __syncthreads();
    short8 aH[4], aL[4], bH[4], bL[4];
    #pragma unroll
    for (int m = 0; m < 4; ++m) {
      int r = (wr * 64 + m * 16 + ar) * 32 + ko;
      aH[m] = *(short8*)&As_h[r];
      aL[m] = *(short8*)&As_l[r];
    }
    #pragma unroll
    for (int n = 0; n < 4; ++n) {
      int r = (wc * 64 + n * 16 + ar) * 32 + ko;
      bH[n] = *(short8*)&Bs_h[r];
      bL[n] = *(short8*)&Bs_l[r];
    }
    #pragma unroll
    for (int m = 0; m < 4; ++m)
      #pragma unroll
      for (int n = 0; n < 4; ++n) {
        acc[m][n] = __builtin_amdgcn_mfma_f32_16x16x32_bf16(aH[m], bH[n], acc[m][n], 0, 0, 0);
        acc[m][n] = __builtin_amdgcn_mfma_f32_16x16x32_bf16(aH[m], bL[n], acc[m][n], 0, 0, 0);
        acc[m][n] = __builtin_amdgcn_mfma_f32_16x16x32_bf16(aL[m], bH[n], acc[m][n], 0, 0, 0);
      }
  }
  #pragma unroll
  for (int m = 0; m < 4; ++m)
    #pragma unroll
    for (int n = 0; n < 4; ++n) {
      int row0 = m0 + wr * 64 + m * 16 + (l >> 4) * 4;
      int col  = n0 + wc * 64 + n * 16 + ar;
      if (EPI == 1) {
        #pragma unroll
        for (int i = 0; i < 4; ++i)
          Cout[(size_t)(row0 + i) * 1024 + col] = acc[m][n][i] + bias[col];
      } else if (z == 2) {
        int bq = row0 >> 11, s = row0 & 2047, hh = col >> 6, dd = col & 63;
        size_t vb = (((size_t)(bq * 16 + hh)) * 64 + dd) * 2048 + s;
        short4v hv, lv;
        #pragma unroll
        for (int i = 0; i < 4; ++i) {
          float vv = acc[m][n][i] + bias[col];
          short hi, lo; split2(vv, hi, lo);
          hv[i] = hi; lv[i] = lo;
        }
        *(short4v*)&vt_h[vb] = hv;
        *(short4v*)&vt_l[vb] = lv;
      } else {
        #pragma unroll
        for (int i = 0; i < 4; ++i) {
          int row = row0 + i;
          int bq = row >> 11, s = row & 2047, hh = col >> 6, dd = col & 63;
          size_t idx = (size_t)z * M4 + (((size_t)(bq * 16 + hh)) * 2048 + s) * 64 + dd;
          float vv = acc[m][n][i] + bias[col];
          short hi, lo; split2(vv, hi, lo);
          Oh[idx] = hi; Ol[idx] = lo;
        }
      }
    }
}

// ------------- gating: M = sigmoid(bilinear), scale qh/kh in place ------
__global__ void k_gate(short* __restrict__ qh_h, short* __restrict__ qh_l,
                       short* __restrict__ kh_h, short* __restrict__ kh_l,
                       const float* __restrict__ A, const float* __restrict__ U,
                       const float* __restrict__ Wvec, const float* __restrict__ Cc) {
  __shared__ float A0s[4096], A1s[4096];
  __shared__ float rowk[4][64];
  int tid = threadIdx.x, w = tid >> 6, l = tid & 63;
  for (int i = tid; i < 4096; i += 256) { A0s[i] = A[i]; A1s[i] = A[4096 + i]; }
  __syncthreads();
  float u0 = U[l], u1 = U[64 + l];
  float w0 = Wvec[l], w1 = Wvec[64 + l];
  float c0 = Cc[0], c1 = Cc[1];
  for (int rr = 0; rr < 16; ++rr) {
    size_t row = (size_t)blockIdx.x * 64 + w * 16 + rr;
    size_t base = row * 64 + l;
    float qv = bf2f(qh_h[base]) + bf2f(qh_l[base]);
    float kv = bf2f(kh_h[base]) + bf2f(kh_l[base]);
    rowk[w][l] = kv;
    float y0 = 0.f, y1 = 0.f;
    for (int dd = 0; dd < 64; ++dd) {
      float kd = rowk[w][dd];
      y0 = fmaf(kd, A0s[dd * 64 + l], y0);
      y1 = fmaf(kd, A1s[dd * 64 + l], y1);
    }
    float p0 = y0 * qv + u0 * kv + w0 * qv;
    float p1 = y1 * qv + u1 * kv + w1 * qv;
    #pragma unroll
    for (int mm = 1; mm < 64; mm <<= 1) { p0 += __shfl_xor(p0, mm); p1 += __shfl_xor(p1, mm); }
    p0 += c0; p1 += c1;
    float M0 = 1.f / (1.f + expf(-p0));
    float M1 = 1.f / (1.f + expf(-p1));
    short hi, lo;
    split2(qv * M0, hi, lo); qh_h[base] = hi; qh_l[base] = lo;
    split2(kv * M1, hi, lo); kh_h[base] = hi; kh_l[base] = lo;
  }
}

// ---- fused attention v13: K AND V double-buffered one phase ahead ------
__global__ __launch_bounds__(512, 4) void k_attn(
    const short* __restrict__ ph_h, const short* __restrict__ ph_l,
    const short* __restrict__ vt_h, const short* __restrict__ vt_l,
    const float* __restrict__ mask,
    float* __restrict__ attn, short* __restrict__ mh_h, short* __restrict__ mh_l) {
  int bid = blockIdx.x;
  int xcd = bid & 7, slot = bid >> 3;
  int bh = (xcd << 2) | (slot >> 4);
  int s0 = (slot & 15) << 7;
  int b = bh >> 4, h = bh & 15;
  int tid = threadIdx.x, w = tid >> 6, l = tid & 63;
  int ar = l & 15, hi4 = l >> 4, a7 = ar & 7;
  __shared__ __align__(16) short Ksh[2][4096];
  __shared__ __align__(16) short Ksl[2][4096];
  __shared__ __align__(16) short Vsh[2][4096];
  __shared__ __align__(16) short Vsl[2][4096];
  __shared__ __align__(16) short Pb[8][1024];

  const short* kh_h = ph_h + M4;
  const short* kh_l = ph_l + M4;
  const char* gKh = (const char*)kh_h + (size_t)bh * 2048 * 128;
  const char* gKl = (const char*)kh_l + (size_t)bh * 2048 * 128;
  const char* gVh = (const char*)vt_h + (size_t)bh * 64 * 4096;
  const char* gVl = (const char*)vt_l + (size_t)bh * 64 * 4096;
  const float* maskp = mask + (size_t)b * 2048;

  int rowbase = s0 + w * 16;
  size_t qbase = ((size_t)bh * 2048 + rowbase + ar) * 64 + (size_t)hi4 * 8;
  short8 aH0 = *(const short8*)&ph_h[qbase];
  short8 aH1 = *(const short8*)&ph_h[qbase + 32];
  short8 aL0 = *(const short8*)&ph_l[qbase];
  short8 aL1 = *(const short8*)&ph_l[qbase + 32];

  #define STAGE_K(tile, buf) {                                          \
    const char* th_ = gKh + (size_t)(tile) * 8192;                      \
    const char* tl_ = gKl + (size_t)(tile) * 8192;                      \
    int col_ = tid >> 3, j_ = tid & 7;                                  \
    int gs_ = col_ * 128 + ((j_ ^ (col_ & 7)) << 4);                    \
    gload16(th_ + gs_, (char*)&Ksh[buf][0] + tid * 16);                 \
    gload16(tl_ + gs_, (char*)&Ksl[buf][0] + tid * 16);                 \
  }

  #define STAGE_V(tile, buf) {                                          \
    int row_ = tid >> 3, j_ = tid & 7;                                  \
    int gs_ = row_ * 4096 + (tile) * 128 + ((j_ ^ (row_ & 7)) << 4);    \
    gload16(gVh + gs_, (char*)&Vsh[buf][0] + tid * 16);                 \
    gload16(gVl + gs_, (char*)&Vsl[buf][0] + tid * 16);                 \
  }

  #define QKT(buf, tile) {                                              \
    const char* kbh_ = (const char*)&Ksh[buf][0];                       \
    const char* kbl_ = (const char*)&Ksl[buf][0];                       \
    _Pragma("unroll")                                                   \
    for (int n = 0; n < 4; ++n) {                                       \
      int colloc = n * 16 + ar;                                         \
      int cb = colloc * 128;                                            \
      short8 bH0 = *(const short8*)(kbh_ + cb + ((hi4 ^ a7) << 4));     \
      short8 bH1 = *(const short8*)(kbh_ + cb + (((hi4 + 4) ^ a7) << 4));\
      short8 bL0 = *(const short8*)(kbl_ + cb + ((hi4 ^ a7) << 4));     \
      short8 bL1 = *(const short8*)(kbl_ + cb + (((hi4 + 4) ^ a7) << 4));\
      f32x4 c = {0.f,0.f,0.f,0.f};                                      \
      c = __builtin_amdgcn_mfma_f32_16x16x32_bf16(aH0, bH0, c, 0,0,0);  \
      c = __builtin_amdgcn_mfma_f32_16x16x32_bf16(aH1, bH1, c, 0,0,0);  \
      c = __builtin_amdgcn_mfma_f32_16x16x32_bf16(aH0, bL0, c, 0,0,0);  \
      c = __builtin_amdgcn_mfma_f32_16x16x32_bf16(aH1, bL1, c, 0,0,0);  \
      c = __builtin_amdgcn_mfma_f32_16x16x32_bf16(aL0, bH0, c, 0,0,0);  \
      c = __builtin_amdgcn_mfma_f32_16x16x32_bf16(aL1, bH1, c, 0,0,0);  \
      float mv = maskp[(tile) * 64 + colloc] * -1e9f;                   \
      _Pragma("unroll")                                                 \
      for (int i = 0; i < 4; ++i) lg[n][i] = c[i] * 0.125f + mv;        \
    } }

  float ls[4] = {0.f, 0.f, 0.f, 0.f};

  STAGE_K(0, 0);
  #pragma unroll 1
  for (int t = 0; t < 32; ++t) {
    __syncthreads();
    STAGE_K((t + 1) & 31, (t + 1) & 1);
    f32x4 lg[4];
    QKT(t & 1, t);
    #pragma unroll
    for (int n = 0; n < 4; ++n)
      #pragma unroll
      for (int i = 0; i < 4; ++i) ls[i] += __expf(lg[n][i]);
  }
  #pragma unroll
  for (int mk = 1; mk < 16; mk <<= 1)
    #pragma unroll
    for (int i = 0; i < 4; ++i) ls[i] += __shfl_xor(ls[i], mk);
  float invl[4];
  #pragma unroll
  for (int i = 0; i < 4; ++i) invl[i] = 1.f / ls[i];

  f32x4 acc[4];
  #pragma unroll
  for (int dn = 0; dn < 4; ++dn) acc[dn] = {0.f,0.f,0.f,0.f};
  size_t arow = (size_t)bh * 2048 + rowbase;

  STAGE_V(0, 0);
  #pragma unroll 1
  for (int t = 0; t < 32; ++t) {
    __syncthreads();
    if (t < 31) { STAGE_K(t + 1, (t + 1) & 1); STAGE_V(t + 1, (t + 1) & 1); }
    f32x4 lg[4];
    QKT(t & 1, t);
    char* pbw = (char*)&Pb[w][0];
    #pragma unroll
    for (int n = 0; n < 4; ++n) {
      #pragma unroll
      for (int i = 0; i < 4; ++i) {
        float p = __expf(lg[n][i]) * invl[i];
        lg[n][i] = p;
        int r = hi4 * 4 + i;
        int off = (r * 128 + (n * 16 + ar) * 2) ^ ((r & 7) << 4);
        *(short*)(pbw + off) = f2bf(p);
      }
    }
    #pragma unroll
    for (int ks = 0; ks < 2; ++ks) {
      int roff = (ar * 128 + ks * 64 + hi4 * 16) ^ (a7 << 4);
      short8 pah = *(const short8*)(pbw + roff);
      #pragma unroll
      for (int dn = 0; dn < 4; ++dn) {
        int voff = (dn * 16 + ar) * 128 + ((ks * 64 + hi4 * 16) ^ (a7 << 4));
        short8 vH = *(const short8*)((const char*)&Vsh[t & 1][0] + voff);
        short8 vL = *(const short8*)((const char*)&Vsl[t & 1][0] + voff);
        acc[dn] = __builtin_amdgcn_mfma_f32_16x16x32_bf16(pah, vH, acc[dn], 0,0,0);
        acc[dn] = __builtin_amdgcn_mfma_f32_16x16x32_bf16(pah, vL, acc[dn], 0,0,0);
      }
    }
    #pragma unroll
    for (int n = 0; n < 4; ++n)
      #pragma unroll
      for (int i = 0; i < 4; ++i)
        __builtin_nontemporal_store(lg[n][i],
            &attn[(arow + hi4 * 4 + i) * 2048 + t * 64 + n * 16 + ar]);
  }
  #pragma unroll
  for (int dn = 0; dn < 4; ++dn)
    #pragma unroll
    for (int i = 0; i < 4; ++i) {
      short hh, ll; split2(acc[dn][i], hh, ll);
      size_t idx = ((size_t)b * 2048 + rowbase + hi4 * 4 + i) * 1024
                 + h * 64 + dn * 16 + ar;
      mh_h[idx] = hh; mh_l[idx] = ll;
    }
  #undef STAGE_K
  #undef STAGE_V
  #undef QKT
}

// ------------------------------ launcher --------------------------------
extern "C" void kernel_launch(void* const* d_in, const int* in_sizes, int n_in,
                              void* d_out, int out_size, void* d_ws, size_t ws_size,
                              hipStream_t stream) {
  const float* v    = (const float*)d_in[0];
  const float* k    = (const float*)d_in[1];
  const float* q    = (const float*)d_in[2];
  const float* mask = (const float*)d_in[3];
  const float* Wq   = (const float*)d_in[4];
  const float* bq   = (const float*)d_in[5];
  const float* Wk   = (const float*)d_in[6];
  const float* bk   = (const float*)d_in[7];
  const float* Wv   = (const float*)d_in[8];
  const float* bv   = (const float*)d_in[9];
  const float* Wgk  = (const float*)d_in[10];
  const float* bgk  = (const float*)d_in[11];
  const float* Wgq  = (const float*)d_in[12];
  const float* bgq  = (const float*)d_in[13];
  const float* Wm   = (const float*)d_in[14];
  const float* bm   = (const float*)d_in[15];
  const float* Wo   = (const float*)d_in[16];
  const float* bo   = (const float*)d_in[17];
  float* out  = (float*)d_out;
  float* attn = out + OUT_ELE;

  short* xh = (short*)attn;
  short* xl = xh + 3 * M4;

  short* wth  = (short*)d_ws;
  short* wtl  = wth + 4 * 1048576ull;
  short* ph_h = wtl + 4 * 1048576ull;
  short* ph_l = ph_h + 3 * M4;
  short* vt_h = ph_l + 3 * M4;
  short* vt_l = vt_h + M4;
  short* mh_h = vt_l + M4;
  short* mh_l = mh_h + M4;
  float* Ag   = (float*)(mh_l + M4);
  float* Ug   = Ag + 8192;
  float* Wvec = Ug + 128;
  float* Cg   = Wvec + 128;

  k_prep<<<dim3(16514), 256, 0, stream>>>(q, k, v, xh, xl,
                                          Wq, Wk, Wv, Wo, wth, wtl,
                                          Wgk, Wgq, Wm, bgk, bgq, bm,
                                          Ag, Ug, Wvec, Cg);
  k_gemm<0><<<dim3(8, 32, 3), 256, 0, stream>>>(xh, xl, wth, wtl, bq, bk, bv,
                                                nullptr, ph_h, ph_l, vt_h, vt_l);
  k_gate<<<1024, 256, 0, stream>>>(ph_h, ph_l, ph_h + M4, ph_l + M4, Ag, Ug, Wvec, Cg);
  k_attn<<<dim3(512), 512, 0, stream>>>(ph_h, ph_l, vt_h, vt_l, mask,
                                        attn, mh_h, mh_l);
  k_gemm<1><<<dim3(8, 32, 1), 256, 0, stream>>>(mh_h, mh_l,
                                                wth + 3 * 1048576ull, wtl + 3 * 1048576ull,
                                                bo, bo, bo, out, nullptr, nullptr,
                                                nullptr, nullptr);
}